// Round 1
// baseline (1766.424 us; speedup 1.0000x reference)
//
#include <hip/hip_runtime.h>
#include <hip/hip_bf16.h>

#define N_NODES     100000
#define N_EDGES     1600000
#define NFEAT       128
#define DIM         64
#define NGRAPHS     64

// ---------------------------------------------------------------------------
// K1: tx0 = relu(x @ w_lin0 + b_lin0)      [N, 128] @ [128, 64] -> [N, 64]
// Block = 256 threads = 4 groups of 64 lanes. lane = output dim.
// w staged in LDS (32 KB), lane-stride-1 reads (conflict-free).
// x row values are wave-uniform addresses -> broadcast loads, float4-vectorized.
// ---------------------------------------------------------------------------
__global__ __launch_bounds__(256) void lin0_kernel(
    const float* __restrict__ x, const float* __restrict__ w,
    const float* __restrict__ b, float* __restrict__ out)
{
    __shared__ float wl[NFEAT * DIM];            // 32 KB
    for (int i = threadIdx.x; i < NFEAT * DIM; i += 256) wl[i] = w[i];
    __syncthreads();

    const int lane = threadIdx.x & 63;
    const int grp  = threadIdx.x >> 6;           // 0..3
    const int ROWS_PER_GROUP = 8;                // block covers 32 rows
    int r0 = blockIdx.x * (4 * ROWS_PER_GROUP) + grp * ROWS_PER_GROUP;
    const float bv = b[lane];

    for (int i = 0; i < ROWS_PER_GROUP; ++i) {
        int r = r0 + i;
        if (r >= N_NODES) break;                 // rows contiguous per group
        float acc = bv;
        const float4* xr = (const float4*)(x + (size_t)r * NFEAT);
#pragma unroll
        for (int k4 = 0; k4 < NFEAT / 4; ++k4) {
            float4 xv = xr[k4];
            int k = k4 * 4;
            acc = fmaf(xv.x, wl[(k + 0) * DIM + lane], acc);
            acc = fmaf(xv.y, wl[(k + 1) * DIM + lane], acc);
            acc = fmaf(xv.z, wl[(k + 2) * DIM + lane], acc);
            acc = fmaf(xv.w, wl[(k + 3) * DIM + lane], acc);
        }
        out[(size_t)r * DIM + lane] = fmaxf(acc, 0.0f);
    }
}

// ---------------------------------------------------------------------------
// K2: deg[src[e]] += 1.0   (f32 exact for counts << 2^24)
// ---------------------------------------------------------------------------
__global__ __launch_bounds__(256) void deg_kernel(
    const int* __restrict__ src, float* __restrict__ deg)
{
    int e = blockIdx.x * 256 + threadIdx.x;
    if (e < N_EDGES) unsafeAtomicAdd(&deg[src[e]], 1.0f);
}

// ---------------------------------------------------------------------------
// K3: dinv[i] = deg>0 ? 1/sqrt(deg) : 0   (in-place on deg)
// ---------------------------------------------------------------------------
__global__ __launch_bounds__(256) void dinv_kernel(float* __restrict__ deg)
{
    int i = blockIdx.x * 256 + threadIdx.x;
    if (i < N_NODES) {
        float d = deg[i];
        deg[i] = (d > 0.0f) ? rsqrtf(d) : 0.0f;
    }
}

// ---------------------------------------------------------------------------
// K4: tx1[dst] += norm(e) * tx0[src], norm = -dinv[src]*dinv[dst]
// thread t -> (edge e = t/16, quarter-row q = t%16). Wave = 4 edges.
// Row gathers and atomic scatters are 256B-contiguous.
// ---------------------------------------------------------------------------
__global__ __launch_bounds__(256) void scatter_kernel(
    const int* __restrict__ ei, const float* __restrict__ tx0,
    const float* __restrict__ dinv, float* __restrict__ tx1)
{
    long long t = (long long)blockIdx.x * 256 + threadIdx.x;
    if (t >= (long long)N_EDGES * 16) return;
    int e = (int)(t >> 4);
    int q = (int)(t & 15);
    int s = ei[e];
    int d = ei[N_EDGES + e];
    float nrm = -dinv[s] * dinv[d];
    float4 v = *(const float4*)(tx0 + (size_t)s * DIM + q * 4);
    float* dp = tx1 + (size_t)d * DIM + q * 4;
    unsafeAtomicAdd(dp + 0, nrm * v.x);
    unsafeAtomicAdd(dp + 1, nrm * v.y);
    unsafeAtomicAdd(dp + 2, nrm * v.z);
    unsafeAtomicAdd(dp + 3, nrm * v.w);
}

// ---------------------------------------------------------------------------
// K5: h = relu(tx0 @ w0 + tx1 @ w1 + b);  pooled[batch[r]] += h[r]  (fused)
// batch is sorted -> per-group running accumulator, ~1 atomic flush per group.
// ---------------------------------------------------------------------------
__global__ __launch_bounds__(256) void cheb_kernel(
    const float* __restrict__ tx0, const float* __restrict__ tx1,
    const float* __restrict__ w0, const float* __restrict__ w1,
    const float* __restrict__ b, const int* __restrict__ batch,
    float* __restrict__ pooled, float* __restrict__ h)
{
    __shared__ float w0l[DIM * DIM];             // 16 KB
    __shared__ float w1l[DIM * DIM];             // 16 KB
    for (int i = threadIdx.x; i < DIM * DIM; i += 256) {
        w0l[i] = w0[i];
        w1l[i] = w1[i];
    }
    __syncthreads();

    const int lane = threadIdx.x & 63;
    const int grp  = threadIdx.x >> 6;
    const int ROWS_PER_GROUP = 16;               // block covers 64 rows
    int r0 = blockIdx.x * 64 + grp * ROWS_PER_GROUP;
    const float bv = b[lane];

    float acc_pool = 0.0f;
    int cur_g = -1;

    for (int i = 0; i < ROWS_PER_GROUP; ++i) {
        int r = r0 + i;
        if (r >= N_NODES) break;
        float acc = bv;
        const float4* t0 = (const float4*)(tx0 + (size_t)r * DIM);
        const float4* t1 = (const float4*)(tx1 + (size_t)r * DIM);
#pragma unroll
        for (int k4 = 0; k4 < DIM / 4; ++k4) {
            float4 a = t0[k4];
            float4 c = t1[k4];
            int k = k4 * 4;
            acc = fmaf(a.x, w0l[(k + 0) * DIM + lane], acc);
            acc = fmaf(a.y, w0l[(k + 1) * DIM + lane], acc);
            acc = fmaf(a.z, w0l[(k + 2) * DIM + lane], acc);
            acc = fmaf(a.w, w0l[(k + 3) * DIM + lane], acc);
            acc = fmaf(c.x, w1l[(k + 0) * DIM + lane], acc);
            acc = fmaf(c.y, w1l[(k + 1) * DIM + lane], acc);
            acc = fmaf(c.z, w1l[(k + 2) * DIM + lane], acc);
            acc = fmaf(c.w, w1l[(k + 3) * DIM + lane], acc);
        }
        float hv = fmaxf(acc, 0.0f);
        h[(size_t)r * DIM + lane] = hv;

        int g = batch[r];                        // wave-uniform
        if (g != cur_g) {
            if (cur_g >= 0) unsafeAtomicAdd(&pooled[cur_g * DIM + lane], acc_pool);
            cur_g = g;
            acc_pool = 0.0f;
        }
        acc_pool += hv;
    }
    if (cur_g >= 0) unsafeAtomicAdd(&pooled[cur_g * DIM + lane], acc_pool);
}

// ---------------------------------------------------------------------------
extern "C" void kernel_launch(void* const* d_in, const int* in_sizes, int n_in,
                              void* d_out, int out_size, void* d_ws, size_t ws_size,
                              hipStream_t stream)
{
    const float* x      = (const float*)d_in[0];
    const int*   ei     = (const int*)d_in[1];    // [2, E] int32
    const int*   batch  = (const int*)d_in[2];
    const float* w_lin0 = (const float*)d_in[3];
    const float* b_lin0 = (const float*)d_in[4];
    const float* w0     = (const float*)d_in[5];
    const float* w1     = (const float*)d_in[6];
    const float* b_cheb = (const float*)d_in[7];

    float* pooled = (float*)d_out;                       // [64, 64]
    float* h      = (float*)d_out + NGRAPHS * DIM;       // [N, 64]

    // workspace layout
    float* tx0 = (float*)d_ws;                            // N*64 f32 = 25.6 MB
    float* tx1 = tx0 + (size_t)N_NODES * DIM;             // N*64 f32 = 25.6 MB
    float* deg = tx1 + (size_t)N_NODES * DIM;             // N f32    = 0.4 MB

    // zero-init accumulators (d_ws/d_out are poisoned before every call)
    hipMemsetAsync(tx1, 0, (size_t)N_NODES * DIM * sizeof(float), stream);
    hipMemsetAsync(deg, 0, (size_t)N_NODES * sizeof(float), stream);
    hipMemsetAsync(pooled, 0, (size_t)NGRAPHS * DIM * sizeof(float), stream);

    // K1: lin0 (32 rows per block)
    lin0_kernel<<<(N_NODES + 31) / 32, 256, 0, stream>>>(x, w_lin0, b_lin0, tx0);

    // K2: degree
    deg_kernel<<<(N_EDGES + 255) / 256, 256, 0, stream>>>(ei, deg);

    // K3: dinv (in place)
    dinv_kernel<<<(N_NODES + 255) / 256, 256, 0, stream>>>(deg);

    // K4: edge scatter
    long long nthreads = (long long)N_EDGES * 16;
    scatter_kernel<<<(int)((nthreads + 255) / 256), 256, 0, stream>>>(ei, tx0, deg, tx1);

    // K5: cheb combine + relu + pooled (64 rows per block)
    cheb_kernel<<<(N_NODES + 63) / 64, 256, 0, stream>>>(tx0, tx1, w0, w1, b_cheb,
                                                         batch, pooled, h);
}

// Round 2
// 647.164 us; speedup vs baseline: 2.7295x; 2.7295x over previous
//
#include <hip/hip_runtime.h>
#include <hip/hip_bf16.h>

#define N_NODES     100000
#define N_EDGES     1600000
#define NFEAT       128
#define DIM         64
#define NGRAPHS     64

#define SCAN_CHUNK  1024
#define SCAN_NB     ((N_NODES + SCAN_CHUNK - 1) / SCAN_CHUNK)   // 98

// ---------------------------------------------------------------------------
// K1: tx0 = relu(x @ w_lin0 + b_lin0)      [N, 128] @ [128, 64] -> [N, 64]
// ---------------------------------------------------------------------------
__global__ __launch_bounds__(256) void lin0_kernel(
    const float* __restrict__ x, const float* __restrict__ w,
    const float* __restrict__ b, float* __restrict__ out)
{
    __shared__ float wl[NFEAT * DIM];            // 32 KB
    for (int i = threadIdx.x; i < NFEAT * DIM; i += 256) wl[i] = w[i];
    __syncthreads();

    const int lane = threadIdx.x & 63;
    const int grp  = threadIdx.x >> 6;           // 0..3
    const int ROWS_PER_GROUP = 8;                // block covers 32 rows
    int r0 = blockIdx.x * (4 * ROWS_PER_GROUP) + grp * ROWS_PER_GROUP;
    const float bv = b[lane];

    for (int i = 0; i < ROWS_PER_GROUP; ++i) {
        int r = r0 + i;
        if (r >= N_NODES) break;
        float acc = bv;
        const float4* xr = (const float4*)(x + (size_t)r * NFEAT);
#pragma unroll
        for (int k4 = 0; k4 < NFEAT / 4; ++k4) {
            float4 xv = xr[k4];
            int k = k4 * 4;
            acc = fmaf(xv.x, wl[(k + 0) * DIM + lane], acc);
            acc = fmaf(xv.y, wl[(k + 1) * DIM + lane], acc);
            acc = fmaf(xv.z, wl[(k + 2) * DIM + lane], acc);
            acc = fmaf(xv.w, wl[(k + 3) * DIM + lane], acc);
        }
        out[(size_t)r * DIM + lane] = fmaxf(acc, 0.0f);
    }
}

// ---------------------------------------------------------------------------
// K2: histogram — deg_src (for dinv) and cnt_dst (for CSR) in one edge pass
// ---------------------------------------------------------------------------
__global__ __launch_bounds__(256) void hist_kernel(
    const int* __restrict__ ei, int* __restrict__ deg_src, int* __restrict__ cnt_dst)
{
    int e = blockIdx.x * 256 + threadIdx.x;
    if (e < N_EDGES) {
        atomicAdd(&deg_src[ei[e]], 1);
        atomicAdd(&cnt_dst[ei[N_EDGES + e]], 1);
    }
}

// ---------------------------------------------------------------------------
// K3: dinv[i] = deg>0 ? 1/sqrt(deg) : 0
// ---------------------------------------------------------------------------
__global__ __launch_bounds__(256) void dinv_kernel(
    const int* __restrict__ deg, float* __restrict__ dinv)
{
    int i = blockIdx.x * 256 + threadIdx.x;
    if (i < N_NODES) {
        int d = deg[i];
        dinv[i] = (d > 0) ? rsqrtf((float)d) : 0.0f;
    }
}

// ---------------------------------------------------------------------------
// Scan (exclusive) over cnt_dst, 2-level: per-1024-chunk scan + chunk sums
// ---------------------------------------------------------------------------
__global__ __launch_bounds__(256) void scan1_kernel(
    const int* __restrict__ cnt, int* __restrict__ local_scan, int* __restrict__ block_sums)
{
    __shared__ int wsum[4];
    int t = threadIdx.x;
    int idx = blockIdx.x * SCAN_CHUNK + t * 4;
    int v0 = (idx + 0 < N_NODES) ? cnt[idx + 0] : 0;
    int v1 = (idx + 1 < N_NODES) ? cnt[idx + 1] : 0;
    int v2 = (idx + 2 < N_NODES) ? cnt[idx + 2] : 0;
    int v3 = (idx + 3 < N_NODES) ? cnt[idx + 3] : 0;
    int tsum = v0 + v1 + v2 + v3;

    int lane = t & 63, wv = t >> 6;
    int x = tsum;
#pragma unroll
    for (int off = 1; off < 64; off <<= 1) {
        int y = __shfl_up(x, off, 64);
        if (lane >= off) x += y;
    }
    if (lane == 63) wsum[wv] = x;
    __syncthreads();
    int wbase = 0;
    for (int w = 0; w < wv; ++w) wbase += wsum[w];

    int excl = wbase + x - tsum;
    if (idx + 0 < N_NODES) local_scan[idx + 0] = excl; excl += v0;
    if (idx + 1 < N_NODES) local_scan[idx + 1] = excl; excl += v1;
    if (idx + 2 < N_NODES) local_scan[idx + 2] = excl; excl += v2;
    if (idx + 3 < N_NODES) local_scan[idx + 3] = excl;

    if (t == 255) block_sums[blockIdx.x] = wbase + x;
}

__global__ __launch_bounds__(256) void scan2_kernel(int* __restrict__ block_sums, int nb)
{
    __shared__ int wsum[4];
    int t = threadIdx.x;
    int v = (t < nb) ? block_sums[t] : 0;
    int lane = t & 63, wv = t >> 6;
    int x = v;
#pragma unroll
    for (int off = 1; off < 64; off <<= 1) {
        int y = __shfl_up(x, off, 64);
        if (lane >= off) x += y;
    }
    if (lane == 63) wsum[wv] = x;
    __syncthreads();
    int wbase = 0;
    for (int w = 0; w < wv; ++w) wbase += wsum[w];
    if (t < nb) block_sums[t] = wbase + x - v;    // exclusive, in place
}

__global__ __launch_bounds__(256) void scan3_kernel(
    const int* __restrict__ local_scan, const int* __restrict__ block_sums,
    int* __restrict__ offs, int* __restrict__ cursor)
{
    int base = blockIdx.x * SCAN_CHUNK;
    int add = block_sums[blockIdx.x];
    for (int i = threadIdx.x; i < SCAN_CHUNK; i += 256) {
        int idx = base + i;
        if (idx < N_NODES) {
            int v = local_scan[idx] + add;
            offs[idx]   = v;
            cursor[idx] = v;
        }
    }
    if (blockIdx.x == 0 && threadIdx.x == 0) offs[N_NODES] = N_EDGES;
}

// ---------------------------------------------------------------------------
// K4: bucket-scatter edges into dst-CSR (store src index)
// ---------------------------------------------------------------------------
__global__ __launch_bounds__(256) void csr_scatter_kernel(
    const int* __restrict__ ei, int* __restrict__ cursor, int* __restrict__ csr_src)
{
    int e = blockIdx.x * 256 + threadIdx.x;
    if (e < N_EDGES) {
        int s = ei[e];
        int d = ei[N_EDGES + e];
        int pos = atomicAdd(&cursor[d], 1);
        csr_src[pos] = s;
    }
}

// ---------------------------------------------------------------------------
// K5: gather — tx1[d] = -dinv[d] * sum_{src in CSR[d]} dinv[src] * tx0[src]
// One wave per node; 4 edge-slots x 16 lanes x float4. No atomics.
// ---------------------------------------------------------------------------
__global__ __launch_bounds__(256) void gather_kernel(
    const int* __restrict__ csr_src, const int* __restrict__ offs,
    const float* __restrict__ tx0, const float* __restrict__ dinv,
    float* __restrict__ tx1)
{
    int node = blockIdx.x * 4 + (threadIdx.x >> 6);
    if (node >= N_NODES) return;
    int lane = threadIdx.x & 63;
    int sub  = lane >> 4;       // edge slot 0..3
    int q    = lane & 15;       // quarter-row

    int beg = offs[node], end = offs[node + 1];
    float4 acc = make_float4(0.f, 0.f, 0.f, 0.f);
    for (int p = beg + sub; p < end; p += 4) {
        int s = csr_src[p];
        float ds = dinv[s];
        float4 v = *(const float4*)(tx0 + (size_t)s * DIM + q * 4);
        acc.x = fmaf(ds, v.x, acc.x);
        acc.y = fmaf(ds, v.y, acc.y);
        acc.z = fmaf(ds, v.z, acc.z);
        acc.w = fmaf(ds, v.w, acc.w);
    }
    // reduce the 4 edge-slots (lanes differing in bits 4,5)
#pragma unroll
    for (int off = 16; off <= 32; off <<= 1) {
        acc.x += __shfl_xor(acc.x, off, 64);
        acc.y += __shfl_xor(acc.y, off, 64);
        acc.z += __shfl_xor(acc.z, off, 64);
        acc.w += __shfl_xor(acc.w, off, 64);
    }
    if (sub == 0) {
        float nd = -dinv[node];
        float4 r = make_float4(nd * acc.x, nd * acc.y, nd * acc.z, nd * acc.w);
        *(float4*)(tx1 + (size_t)node * DIM + q * 4) = r;
    }
}

// ---------------------------------------------------------------------------
// K6: h = relu(tx0 @ w0 + tx1 @ w1 + b);  pooled[batch[r]] += h[r]  (fused)
// ---------------------------------------------------------------------------
__global__ __launch_bounds__(256) void cheb_kernel(
    const float* __restrict__ tx0, const float* __restrict__ tx1,
    const float* __restrict__ w0, const float* __restrict__ w1,
    const float* __restrict__ b, const int* __restrict__ batch,
    float* __restrict__ pooled, float* __restrict__ h)
{
    __shared__ float w0l[DIM * DIM];
    __shared__ float w1l[DIM * DIM];
    for (int i = threadIdx.x; i < DIM * DIM; i += 256) {
        w0l[i] = w0[i];
        w1l[i] = w1[i];
    }
    __syncthreads();

    const int lane = threadIdx.x & 63;
    const int grp  = threadIdx.x >> 6;
    const int ROWS_PER_GROUP = 16;
    int r0 = blockIdx.x * 64 + grp * ROWS_PER_GROUP;
    const float bv = b[lane];

    float acc_pool = 0.0f;
    int cur_g = -1;

    for (int i = 0; i < ROWS_PER_GROUP; ++i) {
        int r = r0 + i;
        if (r >= N_NODES) break;
        float acc = bv;
        const float4* t0 = (const float4*)(tx0 + (size_t)r * DIM);
        const float4* t1 = (const float4*)(tx1 + (size_t)r * DIM);
#pragma unroll
        for (int k4 = 0; k4 < DIM / 4; ++k4) {
            float4 a = t0[k4];
            float4 c = t1[k4];
            int k = k4 * 4;
            acc = fmaf(a.x, w0l[(k + 0) * DIM + lane], acc);
            acc = fmaf(a.y, w0l[(k + 1) * DIM + lane], acc);
            acc = fmaf(a.z, w0l[(k + 2) * DIM + lane], acc);
            acc = fmaf(a.w, w0l[(k + 3) * DIM + lane], acc);
            acc = fmaf(c.x, w1l[(k + 0) * DIM + lane], acc);
            acc = fmaf(c.y, w1l[(k + 1) * DIM + lane], acc);
            acc = fmaf(c.z, w1l[(k + 2) * DIM + lane], acc);
            acc = fmaf(c.w, w1l[(k + 3) * DIM + lane], acc);
        }
        float hv = fmaxf(acc, 0.0f);
        h[(size_t)r * DIM + lane] = hv;

        int g = batch[r];
        if (g != cur_g) {
            if (cur_g >= 0) unsafeAtomicAdd(&pooled[cur_g * DIM + lane], acc_pool);
            cur_g = g;
            acc_pool = 0.0f;
        }
        acc_pool += hv;
    }
    if (cur_g >= 0) unsafeAtomicAdd(&pooled[cur_g * DIM + lane], acc_pool);
}

// ---------------------------------------------------------------------------
extern "C" void kernel_launch(void* const* d_in, const int* in_sizes, int n_in,
                              void* d_out, int out_size, void* d_ws, size_t ws_size,
                              hipStream_t stream)
{
    const float* x      = (const float*)d_in[0];
    const int*   ei     = (const int*)d_in[1];    // [2, E] int32
    const int*   batch  = (const int*)d_in[2];
    const float* w_lin0 = (const float*)d_in[3];
    const float* b_lin0 = (const float*)d_in[4];
    const float* w0     = (const float*)d_in[5];
    const float* w1     = (const float*)d_in[6];
    const float* b_cheb = (const float*)d_in[7];

    float* pooled = (float*)d_out;                       // [64, 64]
    float* h      = (float*)d_out + NGRAPHS * DIM;       // [N, 64]

    // workspace layout (~59.5 MB)
    char* wp = (char*)d_ws;
    float* tx0        = (float*)wp;  wp += (size_t)N_NODES * DIM * sizeof(float);
    float* tx1        = (float*)wp;  wp += (size_t)N_NODES * DIM * sizeof(float);
    float* dinv       = (float*)wp;  wp += (size_t)N_NODES * sizeof(float);
    int*   deg_src    = (int*)wp;    wp += (size_t)N_NODES * sizeof(int);
    int*   cnt_dst    = (int*)wp;    wp += (size_t)N_NODES * sizeof(int);
    int*   local_scan = (int*)wp;    wp += (size_t)N_NODES * sizeof(int);
    int*   offs       = (int*)wp;    wp += (size_t)(N_NODES + 1) * sizeof(int);
    int*   cursor     = (int*)wp;    wp += (size_t)N_NODES * sizeof(int);
    int*   block_sums = (int*)wp;    wp += 256 * sizeof(int);
    int*   csr_src    = (int*)wp;    wp += (size_t)N_EDGES * sizeof(int);

    // zero accumulators (ws/out are poisoned before each call)
    hipMemsetAsync(deg_src, 0, (size_t)N_NODES * sizeof(int), stream);
    hipMemsetAsync(cnt_dst, 0, (size_t)N_NODES * sizeof(int), stream);
    hipMemsetAsync(pooled, 0, (size_t)NGRAPHS * DIM * sizeof(float), stream);

    // lin0: tx0 = relu(x @ w_lin0 + b)
    lin0_kernel<<<(N_NODES + 31) / 32, 256, 0, stream>>>(x, w_lin0, b_lin0, tx0);

    // histograms
    hist_kernel<<<(N_EDGES + 255) / 256, 256, 0, stream>>>(ei, deg_src, cnt_dst);

    // dinv
    dinv_kernel<<<(N_NODES + 255) / 256, 256, 0, stream>>>(deg_src, dinv);

    // scan cnt_dst -> offs, cursor
    scan1_kernel<<<SCAN_NB, 256, 0, stream>>>(cnt_dst, local_scan, block_sums);
    scan2_kernel<<<1, 256, 0, stream>>>(block_sums, SCAN_NB);
    scan3_kernel<<<SCAN_NB, 256, 0, stream>>>(local_scan, block_sums, offs, cursor);

    // CSR build
    csr_scatter_kernel<<<(N_EDGES + 255) / 256, 256, 0, stream>>>(ei, cursor, csr_src);

    // gather -> tx1 (no atomics)
    gather_kernel<<<(N_NODES + 3) / 4, 256, 0, stream>>>(csr_src, offs, tx0, dinv, tx1);

    // cheb combine + relu + pool
    cheb_kernel<<<(N_NODES + 63) / 64, 256, 0, stream>>>(tx0, tx1, w0, w1, b_cheb,
                                                         batch, pooled, h);
}

// Round 4
// 561.786 us; speedup vs baseline: 3.1443x; 1.1520x over previous
//
#include <hip/hip_runtime.h>
#include <hip/hip_bf16.h>

#define N_NODES     100000
#define N_EDGES     1600000
#define NFEAT       128
#define DIM         64
#define NGRAPHS     64

#define SCAN_CHUNK  1024
#define SCAN_NB     ((N_NODES + SCAN_CHUNK - 1) / SCAN_CHUNK)   // 98

#define NCHUNK      8
#define CHUNK_NODES ((N_NODES + NCHUNK - 1) / NCHUNK)           // 12500

__device__ __forceinline__ float bf2f(unsigned short u) {
    return __uint_as_float(((unsigned)u) << 16);
}
__device__ __forceinline__ unsigned short f2bf(float f) {
    unsigned u = __float_as_uint(f);
    u += 0x7fffu + ((u >> 16) & 1u);          // RNE (no NaN possible here)
    return (unsigned short)(u >> 16);
}

// ---------------------------------------------------------------------------
// K1: tx0b = bf16( relu(x @ w_lin0 + b_lin0) )   [N,128]@[128,64] -> [N,64]
// ---------------------------------------------------------------------------
__global__ __launch_bounds__(256) void lin0_kernel(
    const float* __restrict__ x, const float* __restrict__ w,
    const float* __restrict__ b, unsigned short* __restrict__ tx0b)
{
    __shared__ float wl[NFEAT * DIM];            // 32 KB
    for (int i = threadIdx.x; i < NFEAT * DIM; i += 256) wl[i] = w[i];
    __syncthreads();

    const int lane = threadIdx.x & 63;
    const int grp  = threadIdx.x >> 6;           // 0..3
    const int ROWS_PER_GROUP = 8;                // block covers 32 rows
    int r0 = blockIdx.x * (4 * ROWS_PER_GROUP) + grp * ROWS_PER_GROUP;
    const float bv = b[lane];

    for (int i = 0; i < ROWS_PER_GROUP; ++i) {
        int r = r0 + i;
        if (r >= N_NODES) break;
        float acc = bv;
        const float4* xr = (const float4*)(x + (size_t)r * NFEAT);
#pragma unroll
        for (int k4 = 0; k4 < NFEAT / 4; ++k4) {
            float4 xv = xr[k4];
            int k = k4 * 4;
            acc = fmaf(xv.x, wl[(k + 0) * DIM + lane], acc);
            acc = fmaf(xv.y, wl[(k + 1) * DIM + lane], acc);
            acc = fmaf(xv.z, wl[(k + 2) * DIM + lane], acc);
            acc = fmaf(xv.w, wl[(k + 3) * DIM + lane], acc);
        }
        tx0b[(size_t)r * DIM + lane] = f2bf(fmaxf(acc, 0.0f));
    }
}

// ---------------------------------------------------------------------------
// K2: histogram — deg_src (for dinv) and cnt_dst (for CSR) in one edge pass
// ---------------------------------------------------------------------------
__global__ __launch_bounds__(256) void hist_kernel(
    const int* __restrict__ ei, int* __restrict__ deg_src, int* __restrict__ cnt_dst)
{
    int e = blockIdx.x * 256 + threadIdx.x;
    if (e < N_EDGES) {
        atomicAdd(&deg_src[ei[e]], 1);
        atomicAdd(&cnt_dst[ei[N_EDGES + e]], 1);
    }
}

// ---------------------------------------------------------------------------
// Exclusive scan over cnt_dst, 2-level (1024-chunk)
// ---------------------------------------------------------------------------
__global__ __launch_bounds__(256) void scan1_kernel(
    const int* __restrict__ cnt, int* __restrict__ local_scan, int* __restrict__ block_sums)
{
    __shared__ int wsum[4];
    int t = threadIdx.x;
    int idx = blockIdx.x * SCAN_CHUNK + t * 4;
    int v0 = (idx + 0 < N_NODES) ? cnt[idx + 0] : 0;
    int v1 = (idx + 1 < N_NODES) ? cnt[idx + 1] : 0;
    int v2 = (idx + 2 < N_NODES) ? cnt[idx + 2] : 0;
    int v3 = (idx + 3 < N_NODES) ? cnt[idx + 3] : 0;
    int tsum = v0 + v1 + v2 + v3;

    int lane = t & 63, wv = t >> 6;
    int x = tsum;
#pragma unroll
    for (int off = 1; off < 64; off <<= 1) {
        int y = __shfl_up(x, off, 64);
        if (lane >= off) x += y;
    }
    if (lane == 63) wsum[wv] = x;
    __syncthreads();
    int wbase = 0;
    for (int w = 0; w < wv; ++w) wbase += wsum[w];

    int excl = wbase + x - tsum;
    if (idx + 0 < N_NODES) local_scan[idx + 0] = excl; excl += v0;
    if (idx + 1 < N_NODES) local_scan[idx + 1] = excl; excl += v1;
    if (idx + 2 < N_NODES) local_scan[idx + 2] = excl; excl += v2;
    if (idx + 3 < N_NODES) local_scan[idx + 3] = excl;

    if (t == 255) block_sums[blockIdx.x] = wbase + x;
}

__global__ __launch_bounds__(256) void scan2_kernel(int* __restrict__ block_sums, int nb)
{
    __shared__ int wsum[4];
    int t = threadIdx.x;
    int v = (t < nb) ? block_sums[t] : 0;
    int lane = t & 63, wv = t >> 6;
    int x = v;
#pragma unroll
    for (int off = 1; off < 64; off <<= 1) {
        int y = __shfl_up(x, off, 64);
        if (lane >= off) x += y;
    }
    if (lane == 63) wsum[wv] = x;
    __syncthreads();
    int wbase = 0;
    for (int w = 0; w < wv; ++w) wbase += wsum[w];
    if (t < nb) block_sums[t] = wbase + x - v;    // exclusive, in place
}

// scan3 also computes dinv (fused)
__global__ __launch_bounds__(256) void scan3_kernel(
    const int* __restrict__ local_scan, const int* __restrict__ block_sums,
    int* __restrict__ offs, int* __restrict__ cursor,
    const int* __restrict__ deg_src, float* __restrict__ dinv)
{
    int base = blockIdx.x * SCAN_CHUNK;
    int add = block_sums[blockIdx.x];
    for (int i = threadIdx.x; i < SCAN_CHUNK; i += 256) {
        int idx = base + i;
        if (idx < N_NODES) {
            int v = local_scan[idx] + add;
            offs[idx]   = v;
            cursor[idx] = v;
            int dg = deg_src[idx];
            dinv[idx] = (dg > 0) ? rsqrtf((float)dg) : 0.0f;
        }
    }
    if (blockIdx.x == 0 && threadIdx.x == 0) offs[N_NODES] = N_EDGES;
}

// ---------------------------------------------------------------------------
// K4: chunked bucket-scatter into dst-CSR. Writes of each pass land in a
// 0.8 MB csr window -> stays L2-resident, line write-backs merge.
// ---------------------------------------------------------------------------
__global__ __launch_bounds__(256) void csr_scatter_kernel(
    const int* __restrict__ ei, int* __restrict__ cursor, int* __restrict__ csr_src)
{
    const int stride = gridDim.x * 256;
    for (int c = 0; c < NCHUNK; ++c) {
        int lo = c * CHUNK_NODES;
        int hi = lo + CHUNK_NODES;
        for (int e = blockIdx.x * 256 + threadIdx.x; e < N_EDGES; e += stride) {
            int d = ei[N_EDGES + e];
            if (d >= lo && d < hi) {
                int pos = atomicAdd(&cursor[d], 1);
                csr_src[pos] = ei[e];
            }
        }
    }
}

// ---------------------------------------------------------------------------
// K5: gather — tx1[d] = -dinv[d] * sum_{src in CSR[d]} dinv[src] * tx0[src]
// One wave per node; 4 edge-slots x 16 lanes x bf16x4 (8B). No atomics.
// ---------------------------------------------------------------------------
__global__ __launch_bounds__(256) void gather_kernel(
    const int* __restrict__ csr_src, const int* __restrict__ offs,
    const unsigned short* __restrict__ tx0b, const float* __restrict__ dinv,
    float* __restrict__ tx1)
{
    int node = blockIdx.x * 4 + (threadIdx.x >> 6);
    if (node >= N_NODES) return;
    int lane = threadIdx.x & 63;
    int sub  = lane >> 4;       // edge slot 0..3
    int q    = lane & 15;       // quarter-row

    int beg = offs[node], end = offs[node + 1];
    float4 acc = make_float4(0.f, 0.f, 0.f, 0.f);
    for (int p = beg + sub; p < end; p += 4) {
        int s = csr_src[p];
        float ds = dinv[s];
        ushort4 v = *(const ushort4*)(tx0b + (size_t)s * DIM + q * 4);
        acc.x = fmaf(ds, bf2f(v.x), acc.x);
        acc.y = fmaf(ds, bf2f(v.y), acc.y);
        acc.z = fmaf(ds, bf2f(v.z), acc.z);
        acc.w = fmaf(ds, bf2f(v.w), acc.w);
    }
#pragma unroll
    for (int off = 16; off <= 32; off <<= 1) {
        acc.x += __shfl_xor(acc.x, off, 64);
        acc.y += __shfl_xor(acc.y, off, 64);
        acc.z += __shfl_xor(acc.z, off, 64);
        acc.w += __shfl_xor(acc.w, off, 64);
    }
    if (sub == 0) {
        float nd = -dinv[node];
        float4 r = make_float4(nd * acc.x, nd * acc.y, nd * acc.z, nd * acc.w);
        *(float4*)(tx1 + (size_t)node * DIM + q * 4) = r;
    }
}

// ---------------------------------------------------------------------------
// K6: h = relu(tx0 @ w0 + tx1 @ w1 + b);  pooled[batch[r]] += h[r]  (fused)
// ---------------------------------------------------------------------------
__global__ __launch_bounds__(256) void cheb_kernel(
    const unsigned short* __restrict__ tx0b, const float* __restrict__ tx1,
    const float* __restrict__ w0, const float* __restrict__ w1,
    const float* __restrict__ b, const int* __restrict__ batch,
    float* __restrict__ pooled, float* __restrict__ h)
{
    __shared__ float w0l[DIM * DIM];
    __shared__ float w1l[DIM * DIM];
    for (int i = threadIdx.x; i < DIM * DIM; i += 256) {
        w0l[i] = w0[i];
        w1l[i] = w1[i];
    }
    __syncthreads();

    const int lane = threadIdx.x & 63;
    const int grp  = threadIdx.x >> 6;
    const int ROWS_PER_GROUP = 16;
    int r0 = blockIdx.x * 64 + grp * ROWS_PER_GROUP;
    const float bv = b[lane];

    float acc_pool = 0.0f;
    int cur_g = -1;

    for (int i = 0; i < ROWS_PER_GROUP; ++i) {
        int r = r0 + i;
        if (r >= N_NODES) break;
        float acc = bv;
        const ushort4* t0 = (const ushort4*)(tx0b + (size_t)r * DIM);
        const float4*  t1 = (const float4*)(tx1 + (size_t)r * DIM);
#pragma unroll
        for (int k4 = 0; k4 < DIM / 4; ++k4) {
            ushort4 a = t0[k4];
            float4  c = t1[k4];
            int k = k4 * 4;
            acc = fmaf(bf2f(a.x), w0l[(k + 0) * DIM + lane], acc);
            acc = fmaf(bf2f(a.y), w0l[(k + 1) * DIM + lane], acc);
            acc = fmaf(bf2f(a.z), w0l[(k + 2) * DIM + lane], acc);
            acc = fmaf(bf2f(a.w), w0l[(k + 3) * DIM + lane], acc);
            acc = fmaf(c.x, w1l[(k + 0) * DIM + lane], acc);
            acc = fmaf(c.y, w1l[(k + 1) * DIM + lane], acc);
            acc = fmaf(c.z, w1l[(k + 2) * DIM + lane], acc);
            acc = fmaf(c.w, w1l[(k + 3) * DIM + lane], acc);
        }
        float hv = fmaxf(acc, 0.0f);
        h[(size_t)r * DIM + lane] = hv;

        int g = batch[r];                        // sorted, wave-uniform
        if (g != cur_g) {
            if (cur_g >= 0) unsafeAtomicAdd(&pooled[cur_g * DIM + lane], acc_pool);
            cur_g = g;
            acc_pool = 0.0f;
        }
        acc_pool += hv;
    }
    if (cur_g >= 0) unsafeAtomicAdd(&pooled[cur_g * DIM + lane], acc_pool);
}

// ---------------------------------------------------------------------------
extern "C" void kernel_launch(void* const* d_in, const int* in_sizes, int n_in,
                              void* d_out, int out_size, void* d_ws, size_t ws_size,
                              hipStream_t stream)
{
    const float* x      = (const float*)d_in[0];
    const int*   ei     = (const int*)d_in[1];    // [2, E] int32
    const int*   batch  = (const int*)d_in[2];
    const float* w_lin0 = (const float*)d_in[3];
    const float* b_lin0 = (const float*)d_in[4];
    const float* w0     = (const float*)d_in[5];
    const float* w1     = (const float*)d_in[6];
    const float* b_cheb = (const float*)d_in[7];

    float* pooled = (float*)d_out;                       // [64, 64]
    float* h      = (float*)d_out + NGRAPHS * DIM;       // [N, 64]

    // workspace layout (~47.6 MB)
    char* wp = (char*)d_ws;
    unsigned short* tx0b = (unsigned short*)wp; wp += (size_t)N_NODES * DIM * sizeof(unsigned short);
    float* tx1        = (float*)wp;  wp += (size_t)N_NODES * DIM * sizeof(float);
    float* dinv       = (float*)wp;  wp += (size_t)N_NODES * sizeof(float);
    int*   deg_src    = (int*)wp;    wp += (size_t)N_NODES * sizeof(int);
    int*   cnt_dst    = (int*)wp;    wp += (size_t)N_NODES * sizeof(int);   // adjacent to deg_src
    int*   local_scan = (int*)wp;    wp += (size_t)N_NODES * sizeof(int);
    int*   offs       = (int*)wp;    wp += (size_t)(N_NODES + 1) * sizeof(int);
    int*   cursor     = (int*)wp;    wp += (size_t)N_NODES * sizeof(int);
    int*   block_sums = (int*)wp;    wp += 256 * sizeof(int);
    int*   csr_src    = (int*)wp;    wp += (size_t)N_EDGES * sizeof(int);

    // zero accumulators (deg_src+cnt_dst are adjacent -> one memset)
    hipMemsetAsync(deg_src, 0, (size_t)2 * N_NODES * sizeof(int), stream);
    hipMemsetAsync(pooled, 0, (size_t)NGRAPHS * DIM * sizeof(float), stream);

    // lin0 -> tx0 (bf16)
    lin0_kernel<<<(N_NODES + 31) / 32, 256, 0, stream>>>(x, w_lin0, b_lin0, tx0b);

    // histograms
    hist_kernel<<<(N_EDGES + 255) / 256, 256, 0, stream>>>(ei, deg_src, cnt_dst);

    // scan cnt_dst -> offs, cursor (+ dinv fused)
    scan1_kernel<<<SCAN_NB, 256, 0, stream>>>(cnt_dst, local_scan, block_sums);
    scan2_kernel<<<1, 256, 0, stream>>>(block_sums, SCAN_NB);
    scan3_kernel<<<SCAN_NB, 256, 0, stream>>>(local_scan, block_sums, offs, cursor,
                                              deg_src, dinv);

    // chunked CSR build (grid-resident)
    csr_scatter_kernel<<<2048, 256, 0, stream>>>(ei, cursor, csr_src);

    // gather -> tx1 (no atomics)
    gather_kernel<<<(N_NODES + 3) / 4, 256, 0, stream>>>(csr_src, offs, tx0b, dinv, tx1);

    // cheb combine + relu + pool
    cheb_kernel<<<(N_NODES + 63) / 64, 256, 0, stream>>>(tx0b, tx1, w0, w1, b_cheb,
                                                         batch, pooled, h);
}